// Round 9
// baseline (327.781 us; speedup 1.0000x reference)
//
#include <hip/hip_runtime.h>

typedef unsigned short u16;
typedef __bf16 bf16x8 __attribute__((ext_vector_type(8)));
typedef float f32x4 __attribute__((ext_vector_type(4)));

#define HH  56
#define WW  56
#define HW  3136      // 56*56
#define CC  256
#define NB  8
#define CKP 2048      // c*7 padded to c*8: channel j's taps = cols j*8..j*8+7
#define KS1 4         // split-K factor GEMM1 (49 iters -> 12/12/12/13)
#define KS2 2         // split-K factor GEMM2 (32 iters -> 16/16)

// round-to-nearest-even fp32 -> bf16 (bit pattern)
__device__ __forceinline__ u16 f2bf(float f) {
  unsigned int u = __float_as_uint(f);
  u += 0x7fffu + ((u >> 16) & 1u);
  return (u16)(u >> 16);
}
__device__ __forceinline__ float bf2f(u16 v) {
  return __uint_as_float((unsigned)v << 16);
}

// ---------------------------------------------------------------------------
// pass1: t1b = bf16(p1w * x), xb = bf16(x).  Fully coalesced float4 reads.
// grid = N*C*HW/4/256 = 6272
// ---------------------------------------------------------------------------
__global__ void pass1(const float* __restrict__ x, const float* __restrict__ p1w,
                      u16* __restrict__ t1b, u16* __restrict__ xb) {
  int i = blockIdx.x * 256 + threadIdx.x;        // over N*C*HW/4
  int cw = i % (CC * HW / 4);                    // p1w broadcast over n
  float4 xv = ((const float4*)x)[i];
  float4 wv = ((const float4*)p1w)[cw];
  uint2 xo = make_uint2((unsigned)f2bf(xv.x) | ((unsigned)f2bf(xv.y) << 16),
                        (unsigned)f2bf(xv.z) | ((unsigned)f2bf(xv.w) << 16));
  ((uint2*)xb)[i] = xo;
  uint2 to = make_uint2((unsigned)f2bf(xv.x * wv.x) | ((unsigned)f2bf(xv.y * wv.y) << 16),
                        (unsigned)f2bf(xv.z * wv.z) | ((unsigned)f2bf(xv.w * wv.w) << 16));
  ((uint2*)t1b)[i] = to;
}

// ---------------------------------------------------------------------------
// gemm1f: fused t5-generation NT GEMM (split-K), 128x128 tile, BK=64.
//   C[i][j*8+k] = sum_p xb[i,p] * (t1[j,p] - pad(t1[(j-1)%C, p+k-3]))
// K-loop v2: A-frags load global->VGPR directly (no As LDS, no DMA drain at
// barrier); B double-buffered in LDS, ONE barrier/iter -> B-gen(it+1) VALU
// overlaps MFMA(it).  Writes fp32 partials Cp[ks][nb][256][CKP].
// grid = (2, 16, NB*KS1)
// ---------------------------------------------------------------------------
__global__ __launch_bounds__(256)
void gemm1f(const u16* __restrict__ A, const u16* __restrict__ t1b,
            float* __restrict__ Cp) {
  __shared__ u16 Bs[2 * 128 * 64];   // 32 KB double buffer

  const int z = blockIdx.z, nb = z / KS1, ks = z % KS1;
  const int it0 = 49 * ks / KS1, it1 = 49 * (ks + 1) / KS1;
  const u16* Ab  = A   + (long)nb * CC * HW;
  const u16* t1n = t1b + (long)nb * CC * HW;
  const int m0 = blockIdx.x * 128, n0 = blockIdx.y * 128;
  const int jb = blockIdx.y * 16;                 // first channel of tile
  const int t = threadIdx.x;
  const int lane = t & 63, wave = t >> 6;
  const int wm = wave & 1, wn = wave >> 1;        // 2x2 waves, 64x64 each
  const int lm = lane & 15, quad = lane >> 4;

  // B-gen mapping
  const int jl = (t >> 3) & 15, pc = t & 7, hf = t >> 7;
  const int j  = jb + jl;
  const int jm = (j + CC - 1) & (CC - 1);
  const u16* arow = t1n + (long)j  * HW;
  const u16* wrow = t1n + (long)jm * HW;

  f32x4 acc[4][4];
#pragma unroll
  for (int a = 0; a < 4; ++a)
#pragma unroll
    for (int b = 0; b < 4; ++b) acc[a][b] = (f32x4)0.0f;

  // B-gen for one K-iter into buffer `buf` (verified R7 math, unchanged)
  auto genB = [&](int it, int buf) {
    const int k0 = it * 64;
    const int p8 = k0 + pc * 8;
    u16* Bp = &Bs[buf * 8192];
    u16 Ar[8], Wd[24];                       // window = flat [p8-8, p8+16)
    *(uint4*)Ar = *(const uint4*)&arow[p8];
#pragma unroll
    for (int L = 0; L < 3; ++L) {
      int ad = p8 - 8 + L * 8;
      ad = ad < 0 ? 0 : (ad > HW - 8 ? HW - 8 : ad);  // garbage only at masked idx
      *(uint4*)&Wd[L * 8] = *(const uint4*)&wrow[ad];
    }
    int w0t = p8 % 56;
    float Af[8];
#pragma unroll
    for (int e = 0; e < 8; ++e) Af[e] = bf2f(Ar[e]);
    if (hf == 0) {                           // k = 0..3
#pragma unroll
      for (int k = 0; k < 4; ++k) {
        u16 v[8];
#pragma unroll
        for (int e = 0; e < 8; ++e) {
          int w = w0t + e; if (w >= 56) w -= 56;
          float tap = ((unsigned)(w + k - 3) < 56u) ? bf2f(Wd[e + k + 5]) : 0.f;
          v[e] = f2bf(Af[e] - tap);
        }
        *(uint4*)&Bp[(jl * 8 + k) * 64 + (pc ^ k) * 8] = make_uint4(
            v[0] | ((unsigned)v[1] << 16), v[2] | ((unsigned)v[3] << 16),
            v[4] | ((unsigned)v[5] << 16), v[6] | ((unsigned)v[7] << 16));
      }
    } else {                                 // k = 4..6 + pad row 7
#pragma unroll
      for (int k = 4; k < 7; ++k) {
        u16 v[8];
#pragma unroll
        for (int e = 0; e < 8; ++e) {
          int w = w0t + e; if (w >= 56) w -= 56;
          float tap = ((unsigned)(w + k - 3) < 56u) ? bf2f(Wd[e + k + 5]) : 0.f;
          v[e] = f2bf(Af[e] - tap);
        }
        *(uint4*)&Bp[(jl * 8 + k) * 64 + (pc ^ k) * 8] = make_uint4(
            v[0] | ((unsigned)v[1] << 16), v[2] | ((unsigned)v[3] << 16),
            v[4] | ((unsigned)v[5] << 16), v[6] | ((unsigned)v[7] << 16));
      }
      *(uint4*)&Bp[(jl * 8 + 7) * 64 + (pc ^ 7) * 8] = make_uint4(0, 0, 0, 0);
    }
  };

  genB(it0, 0);
  __syncthreads();

  for (int it = it0; it < it1; ++it) {
    const int k0 = it * 64;
    const int cb = (it - it0) & 1;
    // MFMA on Bs[cb]; A-frags straight from global (L2-hot, 16B/lane)
#pragma unroll
    for (int kk = 0; kk < 2; ++kk) {
      const int phys = ((kk * 4 + quad) ^ (lm & 7)) * 8;
      bf16x8 af[4], bv[4];
#pragma unroll
      for (int mi = 0; mi < 4; ++mi)
        af[mi] = *(const bf16x8*)&Ab[(long)(m0 + wm * 64 + mi * 16 + lm) * HW
                                     + k0 + (kk * 4 + quad) * 8];
#pragma unroll
      for (int ni = 0; ni < 4; ++ni)
        bv[ni] = *(const bf16x8*)&Bs[cb * 8192 + (wn * 64 + ni * 16 + lm) * 64 + phys];
#pragma unroll
      for (int mi = 0; mi < 4; ++mi)
#pragma unroll
        for (int ni = 0; ni < 4; ++ni)
          acc[mi][ni] = __builtin_amdgcn_mfma_f32_16x16x32_bf16(
              af[mi], bv[ni], acc[mi][ni], 0, 0, 0);
    }
    // overlap: generate next iter's B into the other buffer (clamped on last)
    int itn = it + 1 < it1 ? it + 1 : it;
    genB(itn, cb ^ 1);
    __syncthreads();
  }

  // fp32 partial store; C/D layout: col = lane&15, row = quad*4 + reg
  float* Cb = Cp + ((long)ks * NB + nb) * (long)CC * CKP;
#pragma unroll
  for (int mi = 0; mi < 4; ++mi)
#pragma unroll
    for (int ni = 0; ni < 4; ++ni) {
      int rb = m0 + wm * 64 + mi * 16 + quad * 4;
      int cg = n0 + wn * 64 + ni * 16 + lm;
#pragma unroll
      for (int r = 0; r < 4; ++r)
        Cb[(long)(rb + r) * CKP + cg] = acc[mi][ni][r];
    }
}

// ---------------------------------------------------------------------------
// reduce1: t7 = bf16((sum of KS1 partials) / 56), pad cols (jk%8==7) = 0.
// grid = NB*CC*CKP/4/256 = 4096
// ---------------------------------------------------------------------------
__global__ void reduce1(const float* __restrict__ p1, u16* __restrict__ t7) {
  const int i = blockIdx.x * 256 + threadIdx.x;
  const long S = (long)NB * CC * CKP / 4;
  float4 a = ((const float4*)p1)[i];
  float4 b = ((const float4*)p1)[i + S];
  float4 c = ((const float4*)p1)[i + 2 * S];
  float4 d = ((const float4*)p1)[i + 3 * S];
  const float s = 1.0f / 56.0f;
  float e0 = (a.x + b.x + c.x + d.x) * s;
  float e1 = (a.y + b.y + c.y + d.y) * s;
  float e2 = (a.z + b.z + c.z + d.z) * s;
  float e3 = (a.w + b.w + c.w + d.w) * s;
  u16 w3 = (i & 1) ? (u16)0 : f2bf(e3);   // col%8==7 = elem3 of odd float4s
  ushort4 o = make_ushort4(f2bf(e0), f2bf(e1), f2bf(e2), w3);
  ((ushort4*)t7)[i] = o;
}

// ---------------------------------------------------------------------------
// gemm2f: fused t6T-generation NT GEMM (split-K), 128x64 tile, BK=64.
//   out[i][p] = s2 * sum_{j,k} t7[i][j*8+k] * (xb[j,p] + pad(t1[(j-1)%C, roll(p)+k-3]))
// Same v2 K-loop: direct-global A-frags + double-buffered B, 1 barrier/iter.
// Raw fp32 partials.  grid = (2, 49, NB*KS2)
// ---------------------------------------------------------------------------
__global__ __launch_bounds__(256)
void gemm2f(const u16* __restrict__ A, const u16* __restrict__ xb,
            const u16* __restrict__ t1b, float* __restrict__ Cp) {
  __shared__ u16 Bs[2 * 64 * 64];    // 16 KB double buffer

  const int z = blockIdx.z, nb = z / KS2, ks = z % KS2;
  const int it0 = 16 * ks, it1 = 16 * (ks + 1);   // 32 iters total
  const u16* Ab  = A   + (long)nb * CC * CKP;
  const u16* xbn = xb  + (long)nb * CC * HW;
  const u16* t1n = t1b + (long)nb * CC * HW;
  const int m0 = blockIdx.x * 128, n0 = blockIdx.y * 64;
  const int t = threadIdx.x;
  const int lane = t & 63, wave = t >> 6;
  const int wm = wave & 1, wn = wave >> 1;        // 2(m) x 2(n of 32)
  const int lm = lane & 15, quad = lane >> 4;

  // B-gen mapping: pr = p-row, jg -> 2 channels per thread per iter
  const int pr = t & 63, jg = t >> 6;
  const int p  = n0 + pr;
  const int h  = p / WW, w = p - h * WW;
  const int h2 = (h + HH - 1) % HH;               // roll +1 on h
  const int w2 = (w + 1) % WW;                    // roll -1 on w
  const int swz = pr & 7;

  f32x4 acc[4][2];
#pragma unroll
  for (int a = 0; a < 4; ++a)
#pragma unroll
    for (int b = 0; b < 2; ++b) acc[a][b] = (f32x4)0.0f;

  auto genB = [&](int it, int buf) {
    u16* Bp = &Bs[buf * 4096];
#pragma unroll
    for (int jj = 0; jj < 2; ++jj) {
      const int jch = it * 8 + jg * 2 + jj;
      const int jmm = (jch + CC - 1) & (CC - 1);
      const float xv = bf2f(xbn[(long)jch * HW + p]);
      const u16* trow = t1n + (long)jmm * HW + h2 * WW;
      u16 v[8];
#pragma unroll
      for (int k = 0; k < 7; ++k) {
        int ww = w2 + k - 3;
        int wc = ww < 0 ? 0 : (ww > 55 ? 55 : ww);     // clamped, in-bounds
        float tv = bf2f(trow[wc]);
        float tap = ((unsigned)ww < 56u) ? tv : 0.f;
        v[k] = f2bf(xv + tap);
      }
      v[7] = 0;   // pad slot MUST be finite (A pad col is exact 0)
      *(uint4*)&Bp[pr * 64 + (((jg * 2 + jj) ^ swz) * 8)] = make_uint4(
          v[0] | ((unsigned)v[1] << 16), v[2] | ((unsigned)v[3] << 16),
          v[4] | ((unsigned)v[5] << 16), v[6] | ((unsigned)v[7] << 16));
    }
  };

  genB(it0, 0);
  __syncthreads();

  for (int it = it0; it < it1; ++it) {
    const int k0 = it * 64;
    const int cb = (it - it0) & 1;
#pragma unroll
    for (int kk = 0; kk < 2; ++kk) {
      const int phys = ((kk * 4 + quad) ^ (lm & 7)) * 8;
      bf16x8 af[4], bv[2];
#pragma unroll
      for (int mi = 0; mi < 4; ++mi)
        af[mi] = *(const bf16x8*)&Ab[(long)(m0 + wm * 64 + mi * 16 + lm) * CKP
                                     + k0 + (kk * 4 + quad) * 8];
#pragma unroll
      for (int ni = 0; ni < 2; ++ni)
        bv[ni] = *(const bf16x8*)&Bs[cb * 4096 + (wn * 32 + ni * 16 + lm) * 64 + phys];
#pragma unroll
      for (int mi = 0; mi < 4; ++mi)
#pragma unroll
        for (int ni = 0; ni < 2; ++ni)
          acc[mi][ni] = __builtin_amdgcn_mfma_f32_16x16x32_bf16(
              af[mi], bv[ni], acc[mi][ni], 0, 0, 0);
    }
    int itn = it + 1 < it1 ? it + 1 : it;
    genB(itn, cb ^ 1);
    __syncthreads();
  }

  // raw fp32 partial store (scale applied in reduce2)
  float* Cb = Cp + ((long)ks * NB + nb) * (long)CC * HW;
#pragma unroll
  for (int mi = 0; mi < 4; ++mi)
#pragma unroll
    for (int ni = 0; ni < 2; ++ni) {
      int rb = m0 + wm * 64 + mi * 16 + quad * 4;
      int cg = n0 + wn * 32 + ni * 16 + lm;       // < 3136 always (49*64)
#pragma unroll
      for (int r = 0; r < 4; ++r)
        Cb[(long)(rb + r) * HW + cg] = acc[mi][ni][r];
    }
}

// ---------------------------------------------------------------------------
// reduce2: d_out = (sum of KS2 partials) / sqrt(1792).  fp32 float4.
// grid = NB*CC*HW/4/256 = 6272
// ---------------------------------------------------------------------------
__global__ void reduce2(const float* __restrict__ p2, float* __restrict__ out) {
  const int i = blockIdx.x * 256 + threadIdx.x;
  const long S = (long)NB * CC * HW / 4;
  float4 a = ((const float4*)p2)[i];
  float4 b = ((const float4*)p2)[i + S];
  const float s = 0.023622783f;                   // 1/sqrt(1792)
  float4 o;
  o.x = (a.x + b.x) * s; o.y = (a.y + b.y) * s;
  o.z = (a.z + b.z) * s; o.w = (a.w + b.w) * s;
  ((float4*)out)[i] = o;
}

// ---------------------------------------------------------------------------
// Pipeline: pass1 -> gemm1f -> reduce1 -> gemm2f -> reduce2.
// p2 (51.4 MB) aliases p1 region (67.1 MB, dead after reduce1); stream-ordered.
// Footprint ~101 MB.
// ---------------------------------------------------------------------------
extern "C" void kernel_launch(void* const* d_in, const int* in_sizes, int n_in,
                              void* d_out, int out_size, void* d_ws, size_t ws_size,
                              hipStream_t stream) {
  const float* x   = (const float*)d_in[0];   // (8,256,56,56)
  const float* p1w = (const float*)d_in[1];   // (1,256,56,56)

  char* ws = (char*)d_ws;
  size_t o = 0;
  u16* xb  = (u16*)(ws + o); o += (size_t)NB * CC * HW * 2;          //  12.8 MB
  u16* t1b = (u16*)(ws + o); o += (size_t)NB * CC * HW * 2;          //  12.8 MB
  u16* t7  = (u16*)(ws + o); o += (size_t)NB * CC * CKP * 2;         //   8.4 MB
  float* p1 = (float*)(ws + o); o += (size_t)KS1 * NB * CC * CKP * 4; // 67.1 MB
  float* p2 = p1;   // KS2*NB*CC*HW*4 = 51.4 MB <= 67.1, dead after reduce1

  pass1<<<NB * CC * HW / 4 / 256, 256, 0, stream>>>(x, p1w, t1b, xb);
  gemm1f<<<dim3(2, 16, NB * KS1), 256, 0, stream>>>(xb, t1b, p1);
  reduce1<<<NB * CC * CKP / 4 / 256, 256, 0, stream>>>(p1, t7);
  gemm2f<<<dim3(2, 49, NB * KS2), 256, 0, stream>>>(t7, xb, t1b, p2);
  reduce2<<<NB * CC * HW / 4 / 256, 256, 0, stream>>>(p2, (float*)d_out);
}

// Round 10
// 234.803 us; speedup vs baseline: 1.3960x; 1.3960x over previous
//
#include <hip/hip_runtime.h>

typedef unsigned short u16;
typedef __bf16 bf16x8 __attribute__((ext_vector_type(8)));
typedef float f32x4 __attribute__((ext_vector_type(4)));

#define HH  56
#define WW  56
#define HW  3136      // 56*56
#define CC  256
#define NB  8
#define CKP 2048      // c*7 padded to c*8: channel j's taps = cols j*8..j*8+7
#define KS1 2         // split-K factor GEMM1 (49 iters -> 24/25)

// round-to-nearest-even fp32 -> bf16 (bit pattern)
__device__ __forceinline__ u16 f2bf(float f) {
  unsigned int u = __float_as_uint(f);
  u += 0x7fffu + ((u >> 16) & 1u);
  return (u16)(u >> 16);
}
__device__ __forceinline__ float bf2f(u16 v) {
  return __uint_as_float((unsigned)v << 16);
}

// async global->LDS DMA, 16B per lane; dest = wave-uniform base + lane*16
__device__ __forceinline__ void lds_load16(const void* g, void* l) {
  __builtin_amdgcn_global_load_lds(
      (const __attribute__((address_space(1))) void*)g,
      (__attribute__((address_space(3))) void*)l, 16, 0, 0);
}

// ---------------------------------------------------------------------------
// pass1: t1b = bf16(p1w * x), xb = bf16(x).  Fully coalesced float4 reads.
// grid = N*C*HW/4/256 = 6272
// ---------------------------------------------------------------------------
__global__ void pass1(const float* __restrict__ x, const float* __restrict__ p1w,
                      u16* __restrict__ t1b, u16* __restrict__ xb) {
  int i = blockIdx.x * 256 + threadIdx.x;        // over N*C*HW/4
  int cw = i % (CC * HW / 4);                    // p1w broadcast over n
  float4 xv = ((const float4*)x)[i];
  float4 wv = ((const float4*)p1w)[cw];
  uint2 xo = make_uint2((unsigned)f2bf(xv.x) | ((unsigned)f2bf(xv.y) << 16),
                        (unsigned)f2bf(xv.z) | ((unsigned)f2bf(xv.w) << 16));
  ((uint2*)xb)[i] = xo;
  uint2 to = make_uint2((unsigned)f2bf(xv.x * wv.x) | ((unsigned)f2bf(xv.y * wv.y) << 16),
                        (unsigned)f2bf(xv.z * wv.z) | ((unsigned)f2bf(xv.w * wv.w) << 16));
  ((uint2*)t1b)[i] = to;
}

// ---------------------------------------------------------------------------
// gemm1f: fused t5-generation NT GEMM (split-K), 128x128 tile, BK=64.
//   C[i][j*8+k] = sum_p xb[i,p] * (t1[j,p] - pad(t1[(j-1)%C, p+k-3]))
// K-loop v3: A double-buffered via global_load_lds DMA (coalesced; R9 showed
// direct-global A-frags are lane-strided death), B double-buffered from
// genB VALU, ONE barrier/iter -> prefetch+genB(it+1) overlap MFMA(it) and
// the barrier vmcnt drain waits only on a ~full-body-aged prefetch.
// Writes fp32 partials Cp[ks][nb][256][CKP].  grid = (2, 16, NB*KS1)
// ---------------------------------------------------------------------------
__global__ __launch_bounds__(256)
void gemm1f(const u16* __restrict__ A, const u16* __restrict__ t1b,
            float* __restrict__ Cp) {
  __shared__ u16 As[2 * 8192];   // 2 x 128x64
  __shared__ u16 Bs[2 * 8192];   // 2 x 128x64   (64 KB total)

  const int z = blockIdx.z, nb = z / KS1, ks = z % KS1;
  const int it0 = 49 * ks / KS1, it1 = 49 * (ks + 1) / KS1;
  const u16* Ab  = A   + (long)nb * CC * HW;
  const u16* t1n = t1b + (long)nb * CC * HW;
  const int m0 = blockIdx.x * 128, n0 = blockIdx.y * 128;
  const int jb = blockIdx.y * 16;                 // first channel of tile
  const int t = threadIdx.x;
  const int lane = t & 63, wave = t >> 6;
  const int wm = wave & 1, wn = wave >> 1;        // 2x2 waves, 64x64 each
  const int lm = lane & 15, quad = lane >> 4;

  // B-gen mapping
  const int jl = (t >> 3) & 15, pc = t & 7, hf = t >> 7;
  const int j  = jb + jl;
  const int jm = (j + CC - 1) & (CC - 1);
  const u16* arow = t1n + (long)j  * HW;
  const u16* wrow = t1n + (long)jm * HW;

  f32x4 acc[4][4];
#pragma unroll
  for (int a = 0; a < 4; ++a)
#pragma unroll
    for (int b = 0; b < 4; ++b) acc[a][b] = (f32x4)0.0f;

  // A staging geometry: 1024 chunks of 16B, 4 per thread, XOR swizzle
  int rowc[4], colc[4];
#pragma unroll
  for (int ci = 0; ci < 4; ++ci) {
    int c = t + ci * 256;
    rowc[ci] = c >> 3;
    colc[ci] = ((c & 7) ^ (rowc[ci] & 7)) * 8;
  }

  auto stageA = [&](int it, int buf) {
    const int k0 = it * 64;
#pragma unroll
    for (int ci = 0; ci < 4; ++ci)
      lds_load16(Ab + (long)(m0 + rowc[ci]) * HW + k0 + colc[ci],
                 &As[buf * 8192 + (t + ci * 256) * 8]);
  };

  // B-gen for one K-iter into buffer `buf` (verified R7 math, unchanged)
  auto genB = [&](int it, int buf) {
    const int k0 = it * 64;
    const int p8 = k0 + pc * 8;
    u16* Bp = &Bs[buf * 8192];
    u16 Ar[8], Wd[24];                       // window = flat [p8-8, p8+16)
    *(uint4*)Ar = *(const uint4*)&arow[p8];
#pragma unroll
    for (int L = 0; L < 3; ++L) {
      int ad = p8 - 8 + L * 8;
      ad = ad < 0 ? 0 : (ad > HW - 8 ? HW - 8 : ad);  // garbage only at masked idx
      *(uint4*)&Wd[L * 8] = *(const uint4*)&wrow[ad];
    }
    int w0t = p8 % 56;
    float Af[8];
#pragma unroll
    for (int e = 0; e < 8; ++e) Af[e] = bf2f(Ar[e]);
    if (hf == 0) {                           // k = 0..3
#pragma unroll
      for (int k = 0; k < 4; ++k) {
        u16 v[8];
#pragma unroll
        for (int e = 0; e < 8; ++e) {
          int w = w0t + e; if (w >= 56) w -= 56;
          float tap = ((unsigned)(w + k - 3) < 56u) ? bf2f(Wd[e + k + 5]) : 0.f;
          v[e] = f2bf(Af[e] - tap);
        }
        *(uint4*)&Bp[(jl * 8 + k) * 64 + (pc ^ k) * 8] = make_uint4(
            v[0] | ((unsigned)v[1] << 16), v[2] | ((unsigned)v[3] << 16),
            v[4] | ((unsigned)v[5] << 16), v[6] | ((unsigned)v[7] << 16));
      }
    } else {                                 // k = 4..6 + pad row 7
#pragma unroll
      for (int k = 4; k < 7; ++k) {
        u16 v[8];
#pragma unroll
        for (int e = 0; e < 8; ++e) {
          int w = w0t + e; if (w >= 56) w -= 56;
          float tap = ((unsigned)(w + k - 3) < 56u) ? bf2f(Wd[e + k + 5]) : 0.f;
          v[e] = f2bf(Af[e] - tap);
        }
        *(uint4*)&Bp[(jl * 8 + k) * 64 + (pc ^ k) * 8] = make_uint4(
            v[0] | ((unsigned)v[1] << 16), v[2] | ((unsigned)v[3] << 16),
            v[4] | ((unsigned)v[5] << 16), v[6] | ((unsigned)v[7] << 16));
      }
      *(uint4*)&Bp[(jl * 8 + 7) * 64 + (pc ^ 7) * 8] = make_uint4(0, 0, 0, 0);
    }
  };

  stageA(it0, 0);
  genB(it0, 0);
  __syncthreads();

  for (int it = it0; it < it1; ++it) {
    const int cb = (it - it0) & 1;
    const int itn = it + 1 < it1 ? it + 1 : it;
    stageA(itn, cb ^ 1);                     // DMA in flight across the body
#pragma unroll
    for (int kk = 0; kk < 2; ++kk) {
      const int phys = ((kk * 4 + quad) ^ (lm & 7)) * 8;
      bf16x8 af[4], bv[4];
#pragma unroll
      for (int mi = 0; mi < 4; ++mi)
        af[mi] = *(const bf16x8*)&As[cb * 8192 + (wm * 64 + mi * 16 + lm) * 64 + phys];
#pragma unroll
      for (int ni = 0; ni < 4; ++ni)
        bv[ni] = *(const bf16x8*)&Bs[cb * 8192 + (wn * 64 + ni * 16 + lm) * 64 + phys];
#pragma unroll
      for (int mi = 0; mi < 4; ++mi)
#pragma unroll
        for (int ni = 0; ni < 4; ++ni)
          acc[mi][ni] = __builtin_amdgcn_mfma_f32_16x16x32_bf16(
              af[mi], bv[ni], acc[mi][ni], 0, 0, 0);
    }
    genB(itn, cb ^ 1);                       // VALU overlaps MFMA issue
    __syncthreads();                         // drains aged prefetch + syncs B
  }

  // fp32 partial store; C/D layout: col = lane&15, row = quad*4 + reg
  float* Cb = Cp + ((long)ks * NB + nb) * (long)CC * CKP;
#pragma unroll
  for (int mi = 0; mi < 4; ++mi)
#pragma unroll
    for (int ni = 0; ni < 4; ++ni) {
      int rb = m0 + wm * 64 + mi * 16 + quad * 4;
      int cg = n0 + wn * 64 + ni * 16 + lm;
#pragma unroll
      for (int r = 0; r < 4; ++r)
        Cb[(long)(rb + r) * CKP + cg] = acc[mi][ni][r];
    }
}

// ---------------------------------------------------------------------------
// reduce1: t7 = bf16((sum of KS1 partials) / 56), pad cols (jk%8==7) = 0.
// grid = NB*CC*CKP/4/256 = 4096
// ---------------------------------------------------------------------------
__global__ void reduce1(const float* __restrict__ p1, u16* __restrict__ t7) {
  const int i = blockIdx.x * 256 + threadIdx.x;
  const long S = (long)NB * CC * CKP / 4;
  float4 a = ((const float4*)p1)[i];
  float4 b = ((const float4*)p1)[i + S];
  const float s = 1.0f / 56.0f;
  float e0 = (a.x + b.x) * s;
  float e1 = (a.y + b.y) * s;
  float e2 = (a.z + b.z) * s;
  float e3 = (a.w + b.w) * s;
  u16 w3 = (i & 1) ? (u16)0 : f2bf(e3);   // col%8==7 = elem3 of odd float4s
  ushort4 o = make_ushort4(f2bf(e0), f2bf(e1), f2bf(e2), w3);
  ((ushort4*)t7)[i] = o;
}

// ---------------------------------------------------------------------------
// gemm2f: fused t6T-generation NT GEMM, 128x64 tile, BK=64, NO split-K.
//   out[i][p] = s2 * sum_{j,k} t7[i][j*8+k] * (xb[j,p] + pad(t1[(j-1)%C, roll(p)+k-3]))
// Same v3 K-loop (dbuf A via DMA + dbuf B, 1 barrier/iter).  Writes scaled
// d_out directly (784 blocks ~= full co-residency at 3 blocks/CU).
// grid = (2, 49, NB)
// ---------------------------------------------------------------------------
__global__ __launch_bounds__(256)
void gemm2f(const u16* __restrict__ A, const u16* __restrict__ xb,
            const u16* __restrict__ t1b, float* __restrict__ out) {
  __shared__ u16 As[2 * 8192];   // 2 x 128x64
  __shared__ u16 Bs[2 * 4096];   // 2 x 64x64    (48 KB total)

  const int nb = blockIdx.z;
  const u16* Ab  = A   + (long)nb * CC * CKP;
  const u16* xbn = xb  + (long)nb * CC * HW;
  const u16* t1n = t1b + (long)nb * CC * HW;
  const int m0 = blockIdx.x * 128, n0 = blockIdx.y * 64;
  const int t = threadIdx.x;
  const int lane = t & 63, wave = t >> 6;
  const int wm = wave & 1, wn = wave >> 1;        // 2(m) x 2(n of 32)
  const int lm = lane & 15, quad = lane >> 4;

  // B-gen mapping: pr = p-row, jg -> 2 channels per thread per iter
  const int pr = t & 63, jg = t >> 6;
  const int p  = n0 + pr;
  const int h  = p / WW, w = p - h * WW;
  const int h2 = (h + HH - 1) % HH;               // roll +1 on h
  const int w2 = (w + 1) % WW;                    // roll -1 on w
  const int swz = pr & 7;

  f32x4 acc[4][2];
#pragma unroll
  for (int a = 0; a < 4; ++a)
#pragma unroll
    for (int b = 0; b < 2; ++b) acc[a][b] = (f32x4)0.0f;

  int rowc[4], colc[4];
#pragma unroll
  for (int ci = 0; ci < 4; ++ci) {
    int c = t + ci * 256;
    rowc[ci] = c >> 3;
    colc[ci] = ((c & 7) ^ (rowc[ci] & 7)) * 8;
  }

  auto stageA = [&](int it, int buf) {
    const int k0 = it * 64;
#pragma unroll
    for (int ci = 0; ci < 4; ++ci)
      lds_load16(Ab + (long)(m0 + rowc[ci]) * CKP + k0 + colc[ci],
                 &As[buf * 8192 + (t + ci * 256) * 8]);
  };

  auto genB = [&](int it, int buf) {
    u16* Bp = &Bs[buf * 4096];
#pragma unroll
    for (int jj = 0; jj < 2; ++jj) {
      const int jch = it * 8 + jg * 2 + jj;
      const int jmm = (jch + CC - 1) & (CC - 1);
      const float xv = bf2f(xbn[(long)jch * HW + p]);
      const u16* trow = t1n + (long)jmm * HW + h2 * WW;
      u16 v[8];
#pragma unroll
      for (int k = 0; k < 7; ++k) {
        int ww = w2 + k - 3;
        int wc = ww < 0 ? 0 : (ww > 55 ? 55 : ww);     // clamped, in-bounds
        float tv = bf2f(trow[wc]);
        float tap = ((unsigned)ww < 56u) ? tv : 0.f;
        v[k] = f2bf(xv + tap);
      }
      v[7] = 0;   // pad slot MUST be finite (A pad col is exact 0)
      *(uint4*)&Bp[pr * 64 + (((jg * 2 + jj) ^ swz) * 8)] = make_uint4(
          v[0] | ((unsigned)v[1] << 16), v[2] | ((unsigned)v[3] << 16),
          v[4] | ((unsigned)v[5] << 16), v[6] | ((unsigned)v[7] << 16));
    }
  };

  stageA(0, 0);
  genB(0, 0);
  __syncthreads();

  for (int it = 0; it < 32; ++it) {
    const int cb = it & 1;
    const int itn = it + 1 < 32 ? it + 1 : it;
    stageA(itn, cb ^ 1);
#pragma unroll
    for (int kk = 0; kk < 2; ++kk) {
      const int phys = ((kk * 4 + quad) ^ (lm & 7)) * 8;
      bf16x8 af[4], bv[2];
#pragma unroll
      for (int mi = 0; mi < 4; ++mi)
        af[mi] = *(const bf16x8*)&As[cb * 8192 + (wm * 64 + mi * 16 + lm) * 64 + phys];
#pragma unroll
      for (int ni = 0; ni < 2; ++ni)
        bv[ni] = *(const bf16x8*)&Bs[cb * 4096 + (wn * 32 + ni * 16 + lm) * 64 + phys];
#pragma unroll
      for (int mi = 0; mi < 4; ++mi)
#pragma unroll
        for (int ni = 0; ni < 2; ++ni)
          acc[mi][ni] = __builtin_amdgcn_mfma_f32_16x16x32_bf16(
              af[mi], bv[ni], acc[mi][ni], 0, 0, 0);
    }
    genB(itn, cb ^ 1);
    __syncthreads();
  }

  const float s2 = 0.023622783f;                  // 1/sqrt(1792)
  float* Ob = out + (long)nb * CC * HW;
#pragma unroll
  for (int mi = 0; mi < 4; ++mi)
#pragma unroll
    for (int ni = 0; ni < 2; ++ni) {
      int rb = m0 + wm * 64 + mi * 16 + quad * 4;
      int cg = n0 + wn * 32 + ni * 16 + lm;       // < 3136 always (49*64)
#pragma unroll
      for (int r = 0; r < 4; ++r)
        Ob[(long)(rb + r) * HW + cg] = acc[mi][ni][r] * s2;
    }
}

// ---------------------------------------------------------------------------
// Pipeline: pass1 -> gemm1f -> reduce1 -> gemm2f(-> d_out).  ~68 MB footprint.
// ---------------------------------------------------------------------------
extern "C" void kernel_launch(void* const* d_in, const int* in_sizes, int n_in,
                              void* d_out, int out_size, void* d_ws, size_t ws_size,
                              hipStream_t stream) {
  const float* x   = (const float*)d_in[0];   // (8,256,56,56)
  const float* p1w = (const float*)d_in[1];   // (1,256,56,56)

  char* ws = (char*)d_ws;
  size_t o = 0;
  u16* xb  = (u16*)(ws + o); o += (size_t)NB * CC * HW * 2;          //  12.8 MB
  u16* t1b = (u16*)(ws + o); o += (size_t)NB * CC * HW * 2;          //  12.8 MB
  u16* t7  = (u16*)(ws + o); o += (size_t)NB * CC * CKP * 2;         //   8.4 MB
  float* p1 = (float*)(ws + o); o += (size_t)KS1 * NB * CC * CKP * 4; // 33.6 MB

  pass1<<<NB * CC * HW / 4 / 256, 256, 0, stream>>>(x, p1w, t1b, xb);
  gemm1f<<<dim3(2, 16, NB * KS1), 256, 0, stream>>>(xb, t1b, p1);
  reduce1<<<NB * CC * CKP / 4 / 256, 256, 0, stream>>>(p1, t7);
  gemm2f<<<dim3(2, 49, NB), 256, 0, stream>>>(t7, xb, t1b, (float*)d_out);
}

// Round 11
// 203.797 us; speedup vs baseline: 1.6084x; 1.1521x over previous
//
#include <hip/hip_runtime.h>

typedef unsigned short u16;
typedef __bf16 bf16x8 __attribute__((ext_vector_type(8)));
typedef float f32x4 __attribute__((ext_vector_type(4)));

#define HH  56
#define WW  56
#define HW  3136      // 56*56
#define CC  256
#define NB  8
#define CKP 2048      // c*7 padded to c*8: channel j's taps = cols j*8..j*8+7
#define KS1 4         // split-K factor GEMM1 (49 iters -> 12/12/12/13)

// round-to-nearest-even fp32 -> bf16 (bit pattern) — for non-hot paths
__device__ __forceinline__ u16 f2bf(float f) {
  unsigned int u = __float_as_uint(f);
  u += 0x7fffu + ((u >> 16) & 1u);
  return (u16)(u >> 16);
}
__device__ __forceinline__ float bf2f(u16 v) {
  return __uint_as_float((unsigned)v << 16);
}

// async global->LDS DMA, 16B per lane; dest = wave-uniform base + lane*16
__device__ __forceinline__ void lds_load16(const void* g, void* l) {
  __builtin_amdgcn_global_load_lds(
      (const __attribute__((address_space(1))) void*)g,
      (__attribute__((address_space(3))) void*)l, 16, 0, 0);
}

// ---------------------------------------------------------------------------
// pass1: t1b = bf16(p1w * x), xb = bf16(x).  Fully coalesced float4 reads.
// grid = N*C*HW/4/256 = 6272
// ---------------------------------------------------------------------------
__global__ void pass1(const float* __restrict__ x, const float* __restrict__ p1w,
                      u16* __restrict__ t1b, u16* __restrict__ xb) {
  int i = blockIdx.x * 256 + threadIdx.x;        // over N*C*HW/4
  int cw = i % (CC * HW / 4);                    // p1w broadcast over n
  float4 xv = ((const float4*)x)[i];
  float4 wv = ((const float4*)p1w)[cw];
  uint2 xo = make_uint2((unsigned)f2bf(xv.x) | ((unsigned)f2bf(xv.y) << 16),
                        (unsigned)f2bf(xv.z) | ((unsigned)f2bf(xv.w) << 16));
  ((uint2*)xb)[i] = xo;
  uint2 to = make_uint2((unsigned)f2bf(xv.x * wv.x) | ((unsigned)f2bf(xv.y * wv.y) << 16),
                        (unsigned)f2bf(xv.z * wv.z) | ((unsigned)f2bf(xv.w * wv.w) << 16));
  ((uint2*)t1b)[i] = to;
}

// ---------------------------------------------------------------------------
// gemm1f: fused t5-generation NT GEMM (split-K), 128x128 tile, BK=64.
//   C[i][j*8+k] = sum_p xb[i,p] * (t1[j,p] - pad(t1[(j-1)%C, p+k-3]))
// R8-proven 2-barrier shape (single-buffer As via DMA + genB Bs).  genB uses
// native __bf16 casts + vector stores (hw cvt, RNE) — halves B-gen VALU.
// Writes fp32 partials Cp[ks][nb][256][CKP].  grid = (2, 16, NB*KS1)
// ---------------------------------------------------------------------------
__global__ __launch_bounds__(256)
void gemm1f(const u16* __restrict__ A, const u16* __restrict__ t1b,
            float* __restrict__ Cp) {
  __shared__ u16 As[128 * 64];
  __shared__ u16 Bs[128 * 64];

  const int z = blockIdx.z, nb = z / KS1, ks = z % KS1;
  const int it0 = 49 * ks / KS1, it1 = 49 * (ks + 1) / KS1;
  const u16* Ab  = A   + (long)nb * CC * HW;
  const u16* t1n = t1b + (long)nb * CC * HW;
  const int m0 = blockIdx.x * 128, n0 = blockIdx.y * 128;
  const int jb = blockIdx.y * 16;                 // first channel of tile
  const int t = threadIdx.x;
  const int lane = t & 63, wave = t >> 6;
  const int wm = wave & 1, wn = wave >> 1;        // 2x2 waves, 64x64 each
  const int lm = lane & 15, quad = lane >> 4;

  // B-gen mapping
  const int jl = (t >> 3) & 15, pc = t & 7, hf = t >> 7;
  const int j  = jb + jl;
  const int jm = (j + CC - 1) & (CC - 1);
  const u16* arow = t1n + (long)j  * HW;
  const u16* wrow = t1n + (long)jm * HW;

  f32x4 acc[4][4];
#pragma unroll
  for (int a = 0; a < 4; ++a)
#pragma unroll
    for (int b = 0; b < 4; ++b) acc[a][b] = (f32x4)0.0f;

  // A staging geometry: 1024 chunks of 16B, 4 per thread, XOR swizzle
  int rowc[4], colc[4];
#pragma unroll
  for (int ci = 0; ci < 4; ++ci) {
    int c = t + ci * 256;
    rowc[ci] = c >> 3;
    colc[ci] = ((c & 7) ^ (rowc[ci] & 7)) * 8;
  }

  for (int it = it0; it < it1; ++it) {
    const int k0 = it * 64;
#pragma unroll
    for (int ci = 0; ci < 4; ++ci)
      lds_load16(Ab + (long)(m0 + rowc[ci]) * HW + k0 + colc[ci],
                 &As[(t + ci * 256) * 8]);

    // ---- B-gen: 8 p-values (p8..p8+7), rows jl*8+k ----
    {
      const int p8 = k0 + pc * 8;
      u16 Ar[8], Wd[24];                       // window = flat [p8-8, p8+16)
      *(uint4*)Ar = *(const uint4*)&arow[p8];
#pragma unroll
      for (int L = 0; L < 3; ++L) {
        int ad = p8 - 8 + L * 8;
        ad = ad < 0 ? 0 : (ad > HW - 8 ? HW - 8 : ad);  // garbage only at masked idx
        *(uint4*)&Wd[L * 8] = *(const uint4*)&wrow[ad];
      }
      int w0t = p8 % 56;
      float Af[8];
#pragma unroll
      for (int e = 0; e < 8; ++e) Af[e] = bf2f(Ar[e]);
      if (hf == 0) {                           // k = 0..3
#pragma unroll
        for (int k = 0; k < 4; ++k) {
          __attribute__((aligned(16))) __bf16 v[8];
#pragma unroll
          for (int e = 0; e < 8; ++e) {
            int w = w0t + e; if (w >= 56) w -= 56;
            float tap = ((unsigned)(w + k - 3) < 56u) ? bf2f(Wd[e + k + 5]) : 0.f;
            v[e] = (__bf16)(Af[e] - tap);
          }
          *(uint4*)&Bs[(jl * 8 + k) * 64 + (pc ^ k) * 8] = *(const uint4*)v;
        }
      } else {                                 // k = 4..6 + pad row 7
#pragma unroll
        for (int k = 4; k < 7; ++k) {
          __attribute__((aligned(16))) __bf16 v[8];
#pragma unroll
          for (int e = 0; e < 8; ++e) {
            int w = w0t + e; if (w >= 56) w -= 56;
            float tap = ((unsigned)(w + k - 3) < 56u) ? bf2f(Wd[e + k + 5]) : 0.f;
            v[e] = (__bf16)(Af[e] - tap);
          }
          *(uint4*)&Bs[(jl * 8 + k) * 64 + (pc ^ k) * 8] = *(const uint4*)v;
        }
        *(uint4*)&Bs[(jl * 8 + 7) * 64 + (pc ^ 7) * 8] = make_uint4(0, 0, 0, 0);
      }
    }
    __syncthreads();
#pragma unroll
    for (int kk = 0; kk < 2; ++kk) {
      const int phys = ((kk * 4 + quad) ^ (lm & 7)) * 8;
      bf16x8 af[4], bv[4];
#pragma unroll
      for (int mi = 0; mi < 4; ++mi)
        af[mi] = *(const bf16x8*)&As[(wm * 64 + mi * 16 + lm) * 64 + phys];
#pragma unroll
      for (int ni = 0; ni < 4; ++ni)
        bv[ni] = *(const bf16x8*)&Bs[(wn * 64 + ni * 16 + lm) * 64 + phys];
#pragma unroll
      for (int mi = 0; mi < 4; ++mi)
#pragma unroll
        for (int ni = 0; ni < 4; ++ni)
          acc[mi][ni] = __builtin_amdgcn_mfma_f32_16x16x32_bf16(
              af[mi], bv[ni], acc[mi][ni], 0, 0, 0);
    }
    __syncthreads();
  }

  // fp32 partial store; C/D layout: col = lane&15, row = quad*4 + reg
  float* Cb = Cp + ((long)ks * NB + nb) * (long)CC * CKP;
#pragma unroll
  for (int mi = 0; mi < 4; ++mi)
#pragma unroll
    for (int ni = 0; ni < 4; ++ni) {
      int rb = m0 + wm * 64 + mi * 16 + quad * 4;
      int cg = n0 + wn * 64 + ni * 16 + lm;
#pragma unroll
      for (int r = 0; r < 4; ++r)
        Cb[(long)(rb + r) * CKP + cg] = acc[mi][ni][r];
    }
}

// ---------------------------------------------------------------------------
// reduce1: t7 = bf16((sum of KS1 partials) / 56), pad cols (jk%8==7) = 0.
// grid = NB*CC*CKP/4/256 = 4096
// ---------------------------------------------------------------------------
__global__ void reduce1(const float* __restrict__ p1, u16* __restrict__ t7) {
  const int i = blockIdx.x * 256 + threadIdx.x;
  const long S = (long)NB * CC * CKP / 4;
  float4 a = ((const float4*)p1)[i];
  float4 b = ((const float4*)p1)[i + S];
  float4 c = ((const float4*)p1)[i + 2 * S];
  float4 d = ((const float4*)p1)[i + 3 * S];
  const float s = 1.0f / 56.0f;
  float e0 = (a.x + b.x + c.x + d.x) * s;
  float e1 = (a.y + b.y + c.y + d.y) * s;
  float e2 = (a.z + b.z + c.z + d.z) * s;
  float e3 = (a.w + b.w + c.w + d.w) * s;
  u16 w3 = (i & 1) ? (u16)0 : f2bf(e3);   // col%8==7 = elem3 of odd float4s
  ushort4 o = make_ushort4(f2bf(e0), f2bf(e1), f2bf(e2), w3);
  ((ushort4*)t7)[i] = o;
}

// ---------------------------------------------------------------------------
// gemm2f: fused t6T-generation NT GEMM, 128x64 tile, BK=64, NO split-K.
//   out[i][p] = s2 * sum_{j,k} t7[i][j*8+k] * (xb[j,p] + pad(t1[(j-1)%C, roll(p)+k-3]))
// R7-proven unsplit 2-barrier shape; genB with native __bf16 vector stores.
// Writes scaled d_out directly.  grid = (2, 49, NB)
// ---------------------------------------------------------------------------
__global__ __launch_bounds__(256)
void gemm2f(const u16* __restrict__ A, const u16* __restrict__ xb,
            const u16* __restrict__ t1b, float* __restrict__ out) {
  __shared__ u16 As[128 * 64];
  __shared__ u16 Bs[64 * 64];

  const int nb = blockIdx.z;
  const u16* Ab  = A   + (long)nb * CC * CKP;
  const u16* xbn = xb  + (long)nb * CC * HW;
  const u16* t1n = t1b + (long)nb * CC * HW;
  const int m0 = blockIdx.x * 128, n0 = blockIdx.y * 64;
  const int t = threadIdx.x;
  const int lane = t & 63, wave = t >> 6;
  const int wm = wave & 1, wn = wave >> 1;        // 2(m) x 2(n of 32)
  const int lm = lane & 15, quad = lane >> 4;

  // B-gen mapping: pr = p-row, jg -> 2 channels per thread per iter
  const int pr = t & 63, jg = t >> 6;
  const int p  = n0 + pr;
  const int h  = p / WW, w = p - h * WW;
  const int h2 = (h + HH - 1) % HH;               // roll +1 on h
  const int w2 = (w + 1) % WW;                    // roll -1 on w
  const int swz = pr & 7;

  f32x4 acc[4][2];
#pragma unroll
  for (int a = 0; a < 4; ++a)
#pragma unroll
    for (int b = 0; b < 2; ++b) acc[a][b] = (f32x4)0.0f;

  int rowc[4], colc[4];
#pragma unroll
  for (int ci = 0; ci < 4; ++ci) {
    int c = t + ci * 256;
    rowc[ci] = c >> 3;
    colc[ci] = ((c & 7) ^ (rowc[ci] & 7)) * 8;
  }

  for (int it = 0; it < 32; ++it) {
    const int k0 = it * 64;
#pragma unroll
    for (int ci = 0; ci < 4; ++ci)
      lds_load16(Ab + (long)(m0 + rowc[ci]) * CKP + k0 + colc[ci],
                 &As[(t + ci * 256) * 8]);

    // ---- B-gen: 2 channels, one 16B vector store each ----
#pragma unroll
    for (int jj = 0; jj < 2; ++jj) {
      const int jch = it * 8 + jg * 2 + jj;
      const int jmm = (jch + CC - 1) & (CC - 1);
      const float xv = bf2f(xbn[(long)jch * HW + p]);
      const u16* trow = t1n + (long)jmm * HW + h2 * WW;
      __attribute__((aligned(16))) __bf16 v[8];
#pragma unroll
      for (int k = 0; k < 7; ++k) {
        int ww = w2 + k - 3;
        int wc = ww < 0 ? 0 : (ww > 55 ? 55 : ww);     // clamped, in-bounds
        float tv = bf2f(trow[wc]);
        float tap = ((unsigned)ww < 56u) ? tv : 0.f;
        v[k] = (__bf16)(xv + tap);
      }
      v[7] = (__bf16)0.0f;   // pad slot MUST be finite (A pad col is exact 0)
      *(uint4*)&Bs[pr * 64 + (((jg * 2 + jj) ^ swz) * 8)] = *(const uint4*)v;
    }
    __syncthreads();
#pragma unroll
    for (int kk = 0; kk < 2; ++kk) {
      const int phys = ((kk * 4 + quad) ^ (lm & 7)) * 8;
      bf16x8 af[4], bv[2];
#pragma unroll
      for (int mi = 0; mi < 4; ++mi)
        af[mi] = *(const bf16x8*)&As[(wm * 64 + mi * 16 + lm) * 64 + phys];
#pragma unroll
      for (int ni = 0; ni < 2; ++ni)
        bv[ni] = *(const bf16x8*)&Bs[(wn * 32 + ni * 16 + lm) * 64 + phys];
#pragma unroll
      for (int mi = 0; mi < 4; ++mi)
#pragma unroll
        for (int ni = 0; ni < 2; ++ni)
          acc[mi][ni] = __builtin_amdgcn_mfma_f32_16x16x32_bf16(
              af[mi], bv[ni], acc[mi][ni], 0, 0, 0);
    }
    __syncthreads();
  }

  const float s2 = 0.023622783f;                  // 1/sqrt(1792)
  float* Ob = out + (long)nb * CC * HW;
#pragma unroll
  for (int mi = 0; mi < 4; ++mi)
#pragma unroll
    for (int ni = 0; ni < 2; ++ni) {
      int rb = m0 + wm * 64 + mi * 16 + quad * 4;
      int cg = n0 + wn * 32 + ni * 16 + lm;       // < 3136 always (49*64)
#pragma unroll
      for (int r = 0; r < 4; ++r)
        Ob[(long)(rb + r) * HW + cg] = acc[mi][ni][r] * s2;
    }
}

// ---------------------------------------------------------------------------
// Pipeline: pass1 -> gemm1f -> reduce1 -> gemm2f(-> d_out).  ~101 MB footprint.
// ---------------------------------------------------------------------------
extern "C" void kernel_launch(void* const* d_in, const int* in_sizes, int n_in,
                              void* d_out, int out_size, void* d_ws, size_t ws_size,
                              hipStream_t stream) {
  const float* x   = (const float*)d_in[0];   // (8,256,56,56)
  const float* p1w = (const float*)d_in[1];   // (1,256,56,56)

  char* ws = (char*)d_ws;
  size_t o = 0;
  u16* xb  = (u16*)(ws + o); o += (size_t)NB * CC * HW * 2;          //  12.8 MB
  u16* t1b = (u16*)(ws + o); o += (size_t)NB * CC * HW * 2;          //  12.8 MB
  u16* t7  = (u16*)(ws + o); o += (size_t)NB * CC * CKP * 2;         //   8.4 MB
  float* p1 = (float*)(ws + o); o += (size_t)KS1 * NB * CC * CKP * 4; // 67.1 MB

  pass1<<<NB * CC * HW / 4 / 256, 256, 0, stream>>>(x, p1w, t1b, xb);
  gemm1f<<<dim3(2, 16, NB * KS1), 256, 0, stream>>>(xb, t1b, p1);
  reduce1<<<NB * CC * CKP / 4 / 256, 256, 0, stream>>>(p1, t7);
  gemm2f<<<dim3(2, 49, NB), 256, 0, stream>>>(t7, xb, t1b, (float*)d_out);
}